// Round 1
// baseline (30270.636 us; speedup 1.0000x reference)
//
#include <hip/hip_runtime.h>
#include <hip/hip_bf16.h>

#define Bb 128
#define Tt 1024
#define Dd 512
#define Hh 512
#define Kk 1024
#define BH (Bb*Hh)

typedef __attribute__((ext_vector_type(4))) float  fx4;
typedef __attribute__((ext_vector_type(8))) short  s8;
typedef __attribute__((ext_vector_type(4))) unsigned short us4;

__device__ __forceinline__ unsigned short f2b(float f) {
  union { float f; unsigned u; } v; v.f = f;
  unsigned u = v.u;
  return (unsigned short)((u + 0x7FFFu + ((u >> 16) & 1u)) >> 16);
}
__device__ __forceinline__ float b2f(unsigned short h) {
  union { unsigned u; float f; } v; v.u = ((unsigned)h) << 16;
  return v.f;
}
__device__ __forceinline__ float sigm(float x)   { return 1.f / (1.f + __expf(-x)); }
__device__ __forceinline__ float tanh_f(float x) { return 2.f / (1.f + __expf(-2.f * x)) - 1.f; }

// zero h_f32, c_f32, both bf16 h double-buffers (hi+lo planes each)
__global__ void k_init(float* hf, float* cf, unsigned short* hb0, unsigned short* hb1) {
  int i = blockIdx.x * 256 + threadIdx.x;       // grid covers 2*BH exactly
  if (i < BH) { hf[i] = 0.f; cf[i] = 0.f; }
  hb0[i] = 0; hb1[i] = 0;
}

// Wc[g][k] bf16: k<512 -> W_ih[g][k], else W_hh[g][k-512]
__global__ void k_convw(const float* __restrict__ Wih, const float* __restrict__ Whh,
                        unsigned short* __restrict__ Wc) {
  int i = blockIdx.x * 256 + threadIdx.x;       // over 2048*1024
  int g = i >> 10, k = i & 1023;
  float v = (k < Dd) ? Wih[g * Dd + k] : Whh[g * Hh + (k - Dd)];
  Wc[i] = f2b(v);
}

// X (B,T,D) fp32 -> bf16, 4 elems/thread
__global__ void k_convx(const float* __restrict__ X, unsigned short* __restrict__ Xb) {
  long i = ((long)blockIdx.x * 256 + threadIdx.x) * 4;
  float4 v = *(const float4*)(X + i);
  us4 o;
  o[0] = f2b(v.x); o[1] = f2b(v.y); o[2] = f2b(v.z); o[3] = f2b(v.w);
  *(us4*)(Xb + i) = o;
}

// One time step. Grid (2, 32), block 256 (4 waves).
// Wave tile: 16 batches x 64 gate rows (= 16 hid x 4 gate types as tj).
// MFMA 16x16x32 bf16: a-frag A[m=lane&15][k=quad*8+j] (m=batch),
// b-frag B[k][n=lane&15] = W[gate_row][k], D: row(b)=(quad*4+r), col(g)=lane&15.
template<bool XPRE>
__global__ __launch_bounds__(256, 1) void k_step(
    const float* __restrict__ X, const unsigned short* __restrict__ Xb,
    const unsigned short* __restrict__ Wc,
    const unsigned short* __restrict__ hcur, unsigned short* __restrict__ hnxt,
    float* __restrict__ hf, float* __restrict__ cf,
    const int* __restrict__ lens,
    const float* __restrict__ bih, const float* __restrict__ bhh,
    float* __restrict__ out, int t)
{
  const int wave = threadIdx.x >> 6;
  const int lane = threadIdx.x & 63;
  const int ml   = lane & 15;
  const int quad = lane >> 4;
  const int b0   = blockIdx.x * 64 + wave * 16;
  const int hid  = blockIdx.y * 16 + ml;

  // whole 16-batch subtile frozen (lengths sorted descending -> lens[b0] is tile max)
  if (t >= lens[b0]) {
    #pragma unroll
    for (int r = 0; r < 4; ++r) {
      int b = b0 + quad * 4 + r;
      out[((long)b * Tt + t) * Hh + hid] = 0.f;
      int idx = b * Hh + hid;
      hnxt[idx]      = hcur[idx];
      hnxt[BH + idx] = hcur[BH + idx];
    }
    return;
  }

  fx4 zero = {0.f, 0.f, 0.f, 0.f};
  fx4 acc[4] = {zero, zero, zero, zero};

  const unsigned short* wp  = Wc + (long)hid * Kk + quad * 8;   // b_frag row tj*512+hid
  const unsigned short* ap  = Xb + ((long)(b0 + ml) * Tt + t) * Dd + quad * 8;
  const float*          apf = X  + ((long)(b0 + ml) * Tt + t) * Dd + quad * 8;

  // x-part: K = 0..511
  #pragma unroll 4
  for (int k0 = 0; k0 < Dd; k0 += 32) {
    s8 a;
    if (XPRE) {
      a = *(const s8*)(ap + k0);
    } else {
      float4 x0 = *(const float4*)(apf + k0);
      float4 x1 = *(const float4*)(apf + k0 + 4);
      a[0] = (short)f2b(x0.x); a[1] = (short)f2b(x0.y);
      a[2] = (short)f2b(x0.z); a[3] = (short)f2b(x0.w);
      a[4] = (short)f2b(x1.x); a[5] = (short)f2b(x1.y);
      a[6] = (short)f2b(x1.z); a[7] = (short)f2b(x1.w);
    }
    #pragma unroll
    for (int tj = 0; tj < 4; ++tj) {
      s8 w = *(const s8*)(wp + (long)tj * Hh * Kk + k0);
      acc[tj] = __builtin_amdgcn_mfma_f32_16x16x32_bf16(a, w, acc[tj], 0, 0, 0);
    }
  }

  // h-part: K = 512..1023, two passes (hi plane, then lo plane of split-bf16 h)
  const unsigned short* hp = hcur + (long)(b0 + ml) * Hh + quad * 8;
  #pragma unroll 2
  for (int pass = 0; pass < 2; ++pass) {
    const unsigned short* hpp = hp + (long)pass * BH;
    #pragma unroll 4
    for (int k0 = 0; k0 < Hh; k0 += 32) {
      s8 a = *(const s8*)(hpp + k0);
      #pragma unroll
      for (int tj = 0; tj < 4; ++tj) {
        s8 w = *(const s8*)(wp + (long)tj * Hh * Kk + Dd + k0);
        acc[tj] = __builtin_amdgcn_mfma_f32_16x16x32_bf16(a, w, acc[tj], 0, 0, 0);
      }
    }
  }

  // epilogue: lane-local LSTM cell update (tj = i,f,g,o)
  float bi = bih[hid]          + bhh[hid];
  float bf = bih[Hh + hid]     + bhh[Hh + hid];
  float bg = bih[2 * Hh + hid] + bhh[2 * Hh + hid];
  float bo = bih[3 * Hh + hid] + bhh[3 * Hh + hid];

  #pragma unroll
  for (int r = 0; r < 4; ++r) {
    int b = b0 + quad * 4 + r;
    long oidx = ((long)b * Tt + t) * Hh + hid;
    int idx = b * Hh + hid;
    if (t < lens[b]) {
      float iv = sigm(acc[0][r] + bi);
      float fv = sigm(acc[1][r] + bf);
      float gv = tanh_f(acc[2][r] + bg);
      float ov = sigm(acc[3][r] + bo);
      float cn = fv * cf[idx] + iv * gv;
      float hn = ov * tanh_f(cn);
      cf[idx] = cn;
      hf[idx] = hn;
      unsigned short hi = f2b(hn);
      hnxt[idx]      = hi;
      hnxt[BH + idx] = f2b(hn - b2f(hi));
      out[oidx] = hn;
    } else {
      out[oidx] = 0.f;
      hnxt[idx]      = hcur[idx];
      hnxt[BH + idx] = hcur[BH + idx];
    }
  }
}

__global__ void k_final(const float* __restrict__ hf, const float* __restrict__ cf,
                        float* __restrict__ out) {
  int i = blockIdx.x * 256 + threadIdx.x;       // BH exactly
  long base = (long)Bb * Tt * Hh;
  out[base + i]      = hf[i];
  out[base + BH + i] = cf[i];
}

extern "C" void kernel_launch(void* const* d_in, const int* in_sizes, int n_in,
                              void* d_out, int out_size, void* d_ws, size_t ws_size,
                              hipStream_t stream) {
  const float* X   = (const float*)d_in[0];
  const int*  lens = (const int*)d_in[1];
  const float* Wih = (const float*)d_in[2];
  const float* Whh = (const float*)d_in[3];
  const float* bih = (const float*)d_in[4];
  const float* bhh = (const float*)d_in[5];
  float* out = (float*)d_out;

  char* w = (char*)d_ws;
  float* hf           = (float*)(w);                                  // 256 KB
  float* cf           = (float*)(w + (1u << 18));                     // 256 KB
  unsigned short* hb0 = (unsigned short*)(w + (1u << 19));            // 256 KB (hi+lo)
  unsigned short* hb1 = (unsigned short*)(w + (1u << 19) + (1u << 18));
  unsigned short* Wc  = (unsigned short*)(w + (1u << 20));            // 4 MB
  unsigned short* Xb  = (unsigned short*)(w + (5u << 20));            // 128 MB

  size_t need_full = (size_t)(5u << 20) + (size_t)Bb * Tt * Dd * 2;
  bool xpre = ws_size >= need_full;

  k_init <<<512, 256, 0, stream>>>(hf, cf, hb0, hb1);
  k_convw<<<8192, 256, 0, stream>>>(Wih, Whh, Wc);
  if (xpre) k_convx<<<65536, 256, 0, stream>>>(X, Xb);

  dim3 grid(2, 32);
  for (int t = 0; t < Tt; ++t) {
    unsigned short* cur = (t & 1) ? hb1 : hb0;
    unsigned short* nxt = (t & 1) ? hb0 : hb1;
    if (xpre)
      k_step<true ><<<grid, 256, 0, stream>>>(X, Xb, Wc, cur, nxt, hf, cf, lens, bih, bhh, out, t);
    else
      k_step<false><<<grid, 256, 0, stream>>>(X, Xb, Wc, cur, nxt, hf, cf, lens, bih, bhh, out, t);
  }

  k_final<<<256, 256, 0, stream>>>(hf, cf, out);
}

// Round 2
// 24201.974 us; speedup vs baseline: 1.2508x; 1.2508x over previous
//
#include <hip/hip_runtime.h>
#include <hip/hip_fp16.h>

#define Bb 128
#define Tt 1024
#define Dd 512
#define Hh 512
#define NBX 8     // batch tiles of 16
#define NBY 32    // hid tiles of 16
#define BH (Bb*Hh)

typedef _Float16 f16;
typedef __attribute__((ext_vector_type(8))) _Float16 f16x8;
typedef __attribute__((ext_vector_type(4))) float fx4;

__device__ __forceinline__ float sigm(float x)  { return 1.f / (1.f + __expf(-x)); }
__device__ __forceinline__ float tanh_f(float x){ return 2.f / (1.f + __expf(-2.f * x)) - 1.f; }

// zero hbuf (2 x 128x512 f16 = 65536 uints) and flags (8x1024 ints)
__global__ void k_init(unsigned* hb, unsigned* fl) {
  int i = blockIdx.x * 256 + threadIdx.x;      // grid 256 -> 65536 threads
  hb[i] = 0u;
  if (i < NBX * Tt) fl[i] = 0u;
}

// Wc[g][k] fp16: k<512 -> W_ih[g][k], else W_hh[g][k-512]
__global__ void k_convw(const float* __restrict__ Wih, const float* __restrict__ Whh,
                        f16* __restrict__ Wc) {
  int i = blockIdx.x * 256 + threadIdx.x;      // 2048*1024
  int g = i >> 10, k = i & 1023;
  float v = (k < Dd) ? Wih[g * Dd + k] : Whh[g * Hh + (k - Dd)];
  Wc[i] = (f16)v;
}

// X fp32 -> fp16, 4/thread
__global__ void k_convx(const float* __restrict__ X, f16* __restrict__ Xh) {
  long i = ((long)blockIdx.x * 256 + threadIdx.x) * 4;
  float4 v = *(const float4*)(X + i);
  Xh[i] = (f16)v.x; Xh[i+1] = (f16)v.y; Xh[i+2] = (f16)v.z; Xh[i+3] = (f16)v.w;
}

// Persistent LSTM kernel. Grid (8,32), block 256 = 4 waves.
// Block tile: 16 batches (bx) x 64 gate rows (= 16 hid x 4 types, by).
// K=1024 (512 x | 512 h) split across 4 waves (256 K each): waves 0,1 = x-part,
// waves 2,3 = h-part. W fragments live in 128 VGPRs/wave for the whole kernel.
// Per-step sync: per-bx-group (32 blocks) flag counters, device-scope atomics.
// MFMA 16x16x32 f16: A[m=lane&15][k=quad*8+j] (m=batch),
// B[k][n=lane&15] = W[gate_row][k], D: row(b)=quad*4+r, col(hid)=lane&15.
template<bool XPRE>
__global__ __launch_bounds__(256, 1) void k_rnn(
    const float* __restrict__ X, const f16* __restrict__ Xh,
    const f16* __restrict__ Wc,
    f16* __restrict__ hbuf,            // [2][B*H]
    int* __restrict__ flags,           // [NBX][Tt]
    const int* __restrict__ lens,
    const float* __restrict__ bih, const float* __restrict__ bhh,
    float* __restrict__ out)
{
  const int bx   = blockIdx.x;         // batch tile
  const int by   = blockIdx.y;         // hid tile
  const int tid  = threadIdx.x;
  const int wave = tid >> 6;
  const int lane = tid & 63;
  const int ml   = lane & 15;
  const int quad = lane >> 4;
  const int b0   = bx * 16;
  const int hid0 = by * 16;

  __shared__ float pp[4][4][16][16];   // [wave][type][b][hid] partials, 16 KB

  const int mlen = lens[b0];           // group max length (sorted descending)

  // cell ownership: thread tid <-> (b = tid>>4, hid = tid&15)
  const int cb  = tid >> 4, chd = tid & 15;
  const int myb = b0 + cb,  myh = hid0 + chd;
  const int mylen = lens[myb];
  const float bi_i = bih[myh]        + bhh[myh];
  const float bi_f = bih[Hh + myh]   + bhh[Hh + myh];
  const float bi_g = bih[2*Hh + myh] + bhh[2*Hh + myh];
  const float bi_o = bih[3*Hh + myh] + bhh[3*Hh + myh];
  float c_reg = 0.f, h_reg = 0.f;

  // preload this wave's W fragments: rows = tj*512 + hid0 + ml,
  // k = wave*256 + kc*32 + quad*8  -> 8 kc x 4 tj x 4 VGPRs = 128 VGPRs
  f16x8 wfr[8][4];
  {
    const f16* wp = Wc + (long)(hid0 + ml) * 1024 + wave * 256 + quad * 8;
    #pragma unroll
    for (int kc = 0; kc < 8; ++kc)
      #pragma unroll
      for (int tj = 0; tj < 4; ++tj)
        wfr[kc][tj] = *(const f16x8*)(wp + (long)tj * Hh * 1024 + kc * 32);
  }

  int* gflag = flags + bx * Tt;
  const f16*   xp  = Xh + ((long)(b0 + ml) * Tt) * Dd + wave * 256 + quad * 8;
  const float* xpf = X  + ((long)(b0 + ml) * Tt) * Dd + wave * 256 + quad * 8;

  for (int t = 0; t < mlen; ++t) {
    fx4 zero = {0.f, 0.f, 0.f, 0.f};
    fx4 acc[4] = {zero, zero, zero, zero};

    if (wave < 2) {
      // x-part: no dependency on other blocks' h -> runs before the flag wait
      #pragma unroll
      for (int kc = 0; kc < 8; ++kc) {
        f16x8 a;
        if (XPRE) {
          a = *(const f16x8*)(xp + (long)t * Dd + kc * 32);
        } else {
          float4 x0 = *(const float4*)(xpf + (long)t * Dd + kc * 32);
          float4 x1 = *(const float4*)(xpf + (long)t * Dd + kc * 32 + 4);
          a[0]=(f16)x0.x; a[1]=(f16)x0.y; a[2]=(f16)x0.z; a[3]=(f16)x0.w;
          a[4]=(f16)x1.x; a[5]=(f16)x1.y; a[6]=(f16)x1.z; a[7]=(f16)x1.w;
        }
        #pragma unroll
        for (int tj = 0; tj < 4; ++tj)
          acc[tj] = __builtin_amdgcn_mfma_f32_16x16x32_f16(a, wfr[kc][tj], acc[tj], 0, 0, 0);
      }
      #pragma unroll
      for (int tj = 0; tj < 4; ++tj)
        #pragma unroll
        for (int r = 0; r < 4; ++r)
          pp[wave][tj][quad * 4 + r][ml] = acc[tj][r];
    }

    // wait for all 32 group blocks to have published h_{t-1}
    if (tid == 0 && t > 0) {
      while (__hip_atomic_load(gflag + (t - 1), __ATOMIC_RELAXED,
                               __HIP_MEMORY_SCOPE_AGENT) < NBY)
        __builtin_amdgcn_s_sleep(1);
    }
    __syncthreads();
    __threadfence();   // acquire: invalidate stale cached h

    if (wave >= 2) {
      const f16* hp = hbuf + (long)((t + 1) & 1) * BH
                    + (long)(b0 + ml) * Hh + (wave - 2) * 256 + quad * 8;
      #pragma unroll
      for (int kc = 0; kc < 8; ++kc) {
        f16x8 a = *(const f16x8*)(hp + kc * 32);
        #pragma unroll
        for (int tj = 0; tj < 4; ++tj)
          acc[tj] = __builtin_amdgcn_mfma_f32_16x16x32_f16(a, wfr[kc][tj], acc[tj], 0, 0, 0);
      }
      #pragma unroll
      for (int tj = 0; tj < 4; ++tj)
        #pragma unroll
        for (int r = 0; r < 4; ++r)
          pp[wave][tj][quad * 4 + r][ml] = acc[tj][r];
    }
    __syncthreads();

    // reduce 4 partials + cell update (lane-local: all 4 gate types in-thread)
    {
      float g0 = pp[0][0][cb][chd] + pp[1][0][cb][chd] + pp[2][0][cb][chd] + pp[3][0][cb][chd];
      float g1 = pp[0][1][cb][chd] + pp[1][1][cb][chd] + pp[2][1][cb][chd] + pp[3][1][cb][chd];
      float g2 = pp[0][2][cb][chd] + pp[1][2][cb][chd] + pp[2][2][cb][chd] + pp[3][2][cb][chd];
      float g3 = pp[0][3][cb][chd] + pp[1][3][cb][chd] + pp[2][3][cb][chd] + pp[3][3][cb][chd];
      long oidx = ((long)myb * Tt + t) * Hh + myh;
      if (t < mylen) {
        float iv = sigm(g0 + bi_i);
        float fv = sigm(g1 + bi_f);
        float gv = tanh_f(g2 + bi_g);
        float ov = sigm(g3 + bi_o);
        c_reg = fv * c_reg + iv * gv;
        h_reg = ov * tanh_f(c_reg);
        __builtin_nontemporal_store(h_reg, out + oidx);
      } else {
        __builtin_nontemporal_store(0.f, out + oidx);
      }
      hbuf[(long)(t & 1) * BH + (long)myb * Hh + myh] = (f16)h_reg;
    }
    __syncthreads();

    if (tid == 0) {
      __threadfence();               // release: h_t visible before flag
      atomicAdd(gflag + t, 1);       // device-scope by default on CDNA
    }
  }

  // zero-fill output tail for t >= group max length
  for (int t = mlen; t < Tt; ++t)
    __builtin_nontemporal_store(0.f, out + ((long)myb * Tt + t) * Hh + myh);

  // final h, c
  long base = (long)Bb * Tt * Hh;
  out[base + (long)myb * Hh + myh]      = h_reg;
  out[base + BH + (long)myb * Hh + myh] = c_reg;
}

extern "C" void kernel_launch(void* const* d_in, const int* in_sizes, int n_in,
                              void* d_out, int out_size, void* d_ws, size_t ws_size,
                              hipStream_t stream) {
  const float* X   = (const float*)d_in[0];
  const int*  lens = (const int*)d_in[1];
  const float* Wih = (const float*)d_in[2];
  const float* Whh = (const float*)d_in[3];
  const float* bih = (const float*)d_in[4];
  const float* bhh = (const float*)d_in[5];
  float* out = (float*)d_out;

  char* w = (char*)d_ws;
  f16* hbuf   = (f16*)(w);                        // 256 KB
  int* flags  = (int*)(w + (1u << 18));           // 32 KB
  f16* Wc     = (f16*)(w + (1u << 19));           // 4 MB
  f16* Xh     = (f16*)(w + (9u << 19));           // 128 MB
  size_t need_full = (size_t)(9u << 19) + (size_t)Bb * Tt * Dd * sizeof(f16);
  bool xpre = ws_size >= need_full;

  k_init <<<256,  256, 0, stream>>>((unsigned*)hbuf, (unsigned*)flags);
  k_convw<<<8192, 256, 0, stream>>>(Wih, Whh, Wc);
  if (xpre) k_convx<<<65536, 256, 0, stream>>>(X, Xh);

  dim3 grid(NBX, NBY);
  if (xpre)
    k_rnn<true ><<<grid, 256, 0, stream>>>(X, Xh, Wc, hbuf, flags, lens, bih, bhh, out);
  else
    k_rnn<false><<<grid, 256, 0, stream>>>(X, Xh, Wc, hbuf, flags, lens, bih, bhh, out);
}